// Round 2
// baseline (8903.800 us; speedup 1.0000x reference)
//
#include <hip/hip_runtime.h>
#include <math.h>

#define N_NODES 100000
#define N_EDGES 3200000
#define INC 128
#define HID 64

constexpr int BLK = 256;
constexpr int NBLK_N = (N_NODES + BLK - 1) / BLK;   // 391
constexpr int NBLK_E = (N_EDGES + BLK - 1) / BLK;   // 12500

// zero counts[N_NODES] and stats[3*128]
__global__ void init_zero(int* __restrict__ counts, float* __restrict__ stats) {
    int i = blockIdx.x * blockDim.x + threadIdx.x;
    if (i < N_NODES) counts[i] = 0;
    else if (i < N_NODES + 384) stats[i - N_NODES] = 0.f;
}

__global__ void count_deg(const int* __restrict__ dst, int* __restrict__ counts, int e) {
    int i = blockIdx.x * blockDim.x + threadIdx.x;
    if (i < e) atomicAdd(&counts[dst[i]], 1);
}

// block-level exclusive scan (within block), block totals to bsums
__global__ void scan1(const int* __restrict__ counts, int* __restrict__ offsets,
                      int* __restrict__ bsums, int n) {
    __shared__ int s[BLK];
    int i = blockIdx.x * BLK + threadIdx.x;
    int v = (i < n) ? counts[i] : 0;
    s[threadIdx.x] = v;
    __syncthreads();
    for (int d = 1; d < BLK; d <<= 1) {
        int t = (threadIdx.x >= d) ? s[threadIdx.x - d] : 0;
        __syncthreads();
        s[threadIdx.x] += t;
        __syncthreads();
    }
    if (i < n) offsets[i] = s[threadIdx.x] - v;  // exclusive
    if (threadIdx.x == BLK - 1) bsums[blockIdx.x] = s[BLK - 1];
}

// single-block exclusive scan of block sums (nb <= 512)
__global__ void scan2(int* __restrict__ bsums, int nb) {
    __shared__ int s[512];
    int v = (threadIdx.x < nb) ? bsums[threadIdx.x] : 0;
    s[threadIdx.x] = v;
    __syncthreads();
    for (int d = 1; d < 512; d <<= 1) {
        int t = (threadIdx.x >= d) ? s[threadIdx.x - d] : 0;
        __syncthreads();
        s[threadIdx.x] += t;
        __syncthreads();
    }
    if (threadIdx.x < nb) bsums[threadIdx.x] = s[threadIdx.x] - v;
}

__global__ void scan3(const int* __restrict__ counts, int* __restrict__ offsets,
                      int* __restrict__ cursor, const int* __restrict__ bsums, int n) {
    int i = blockIdx.x * BLK + threadIdx.x;
    if (i < n) {
        int o = offsets[i] + bsums[blockIdx.x];
        offsets[i] = o;
        cursor[i] = o;
        if (i == n - 1) offsets[n] = o + counts[i];
    }
}

// one packed 8B store per edge (halves dirty-line count vs two 4B stores)
__global__ void fill_csr(const int* __restrict__ src, const int* __restrict__ dst,
                         const float* __restrict__ ew, int* __restrict__ cursor,
                         long long* __restrict__ csr, int e) {
    int i = blockIdx.x * blockDim.x + threadIdx.x;
    if (i < e) {
        int d = dst[i];
        int pos = atomicAdd(&cursor[d], 1);
        unsigned long long v = (unsigned int)src[i] |
                               ((unsigned long long)__float_as_uint(ew[i]) << 32);
        __builtin_nontemporal_store((long long)v, csr + pos);
    }
}

// One wave per destination node (grid-stride); lane = channel.
// out = relu(sum ew * t[src] + bias); also accumulates BN sum/sumsq per block.
constexpr int AGG_GRID = 2048;
__global__ __launch_bounds__(BLK) void aggregate_bn(
    const float* __restrict__ t, const int* __restrict__ offs,
    const int2* __restrict__ csr, const float* __restrict__ bias,
    float* __restrict__ out, float* __restrict__ stats, int n)
{
    int lane = threadIdx.x & 63;
    int wid = threadIdx.x >> 6;  // 0..3
    int gwave = blockIdx.x * 4 + wid;
    int nwaves = gridDim.x * 4;
    float bval = bias[lane];
    float bsum = 0.f, bsum2 = 0.f;
    for (int node = gwave; node < n; node += nwaves) {
        int s0 = offs[node], s1 = offs[node + 1];
        float acc = 0.f;
        for (int base = s0; base < s1; base += 64) {
            int idx = base + lane;
            int e = (idx < s1) ? idx : (s1 - 1);
            int2 pk = csr[e];
            int srcv = pk.x;
            float eww = __int_as_float(pk.y);
            int cnt = min(64, s1 - base);
            for (int i = 0; i < cnt; ++i) {
                int s = __shfl(srcv, i, 64);
                float w = __shfl(eww, i, 64);
                acc += w * t[(size_t)s * HID + lane];
            }
        }
        float v = fmaxf(acc + bval, 0.f);
        out[(size_t)node * HID + lane] = v;
        bsum += v;
        bsum2 += v * v;
    }
    __shared__ float ls[4][64], ls2[4][64];
    ls[wid][lane] = bsum;
    ls2[wid][lane] = bsum2;
    __syncthreads();
    if (threadIdx.x < 64) {
        int c = threadIdx.x;
        float a = ls[0][c] + ls[1][c] + ls[2][c] + ls[3][c];
        float b = ls2[0][c] + ls2[1][c] + ls2[2][c] + ls2[3][c];
        atomicAdd(&stats[c], a);
        atomicAdd(&stats[64 + c], b);
    }
}

__global__ void bn_finalize(const float* __restrict__ stats, const float* __restrict__ g,
                            const float* __restrict__ be, float* __restrict__ scsh, float n) {
    int c = threadIdx.x;
    if (c < 64) {
        float mean = stats[c] / n;
        float var = stats[64 + c] / n - mean * mean;
        float s = 1.0f / sqrtf(var + 1e-5f);
        float sc = g[c] * s;
        scsh[c] = sc;
        scsh[64 + c] = be[c] - mean * sc;
    }
}

// Y[r,:] = (trans? X*sc+sh : X)[r,:] @ W   (one thread per row; W in LDS, broadcast reads)
template <int IN, int OUT, bool TRANS>
__global__ __launch_bounds__(BLK) void mm_kernel(
    const float* __restrict__ X, const float* __restrict__ W,
    const float* __restrict__ scale, const float* __restrict__ shift,
    float* __restrict__ Y, int n)
{
    __shared__ float Wl[IN * OUT];
    for (int i = threadIdx.x; i < IN * OUT; i += BLK) Wl[i] = W[i];
    __shared__ float sc[IN], sh[IN];
    if (TRANS) {
        for (int i = threadIdx.x; i < IN; i += BLK) {
            sc[i] = scale[i];
            sh[i] = shift[i];
        }
    }
    __syncthreads();
    int r = blockIdx.x * BLK + threadIdx.x;
    if (r >= n) return;
    float acc[OUT];
#pragma unroll
    for (int j = 0; j < OUT; ++j) acc[j] = 0.f;
    const float4* x4 = reinterpret_cast<const float4*>(X + (size_t)r * IN);
#pragma unroll 2
    for (int k4 = 0; k4 < IN / 4; ++k4) {
        float4 xv = x4[k4];
        float xs[4] = {xv.x, xv.y, xv.z, xv.w};
#pragma unroll
        for (int u = 0; u < 4; ++u) {
            int k = k4 * 4 + u;
            float xk = xs[u];
            if (TRANS) xk = xk * sc[k] + sh[k];
#pragma unroll
            for (int j = 0; j < OUT; ++j) acc[j] += xk * Wl[k * OUT + j];
        }
    }
    float* yr = Y + (size_t)r * OUT;
#pragma unroll
    for (int j = 0; j < OUT; ++j) yr[j] = acc[j];
}

// Fused 3-layer MLP: gelu(gelu((x*sc+sh)@W1+b1)@W2+b2)@W3+b3
// W1 (64x128) + W2 (128x64) in LDS = exactly 64 KB; small arrays via uniform global reads.
__global__ __launch_bounds__(BLK) void mlp_fused(
    const float* __restrict__ X,
    const float* __restrict__ W1, const float* __restrict__ B1,
    const float* __restrict__ W2, const float* __restrict__ B2,
    const float* __restrict__ W3, const float* __restrict__ B3,
    const float* __restrict__ scsh,
    float* __restrict__ Y, int n)
{
    extern __shared__ float lds[];
    float* w1 = lds;            // 64*128
    float* w2 = lds + 64 * 128; // 128*64
    for (int i = threadIdx.x; i < 64 * 128; i += BLK) w1[i] = W1[i];
    for (int i = threadIdx.x; i < 128 * 64; i += BLK) w2[i] = W2[i];
    __syncthreads();
    int r = blockIdx.x * BLK + threadIdx.x;
    if (r >= n) return;

    float h1[128];
#pragma unroll
    for (int j = 0; j < 128; ++j) h1[j] = 0.f;
    const float4* x4 = reinterpret_cast<const float4*>(X + (size_t)r * 64);
#pragma unroll
    for (int k4 = 0; k4 < 16; ++k4) {
        float4 xv = x4[k4];
        float xs[4] = {xv.x, xv.y, xv.z, xv.w};
#pragma unroll
        for (int u = 0; u < 4; ++u) {
            int k = k4 * 4 + u;
            float xk = xs[u] * scsh[k] + scsh[64 + k];
#pragma unroll
            for (int j = 0; j < 128; ++j) h1[j] += xk * w1[k * 128 + j];
        }
    }
#pragma unroll
    for (int j = 0; j < 128; ++j) {
        float v = h1[j] + B1[j];
        h1[j] = 0.5f * v * (1.0f + erff(v * 0.70710678118654752f));
    }
    float h2[64];
#pragma unroll
    for (int j = 0; j < 64; ++j) h2[j] = 0.f;
#pragma unroll
    for (int k = 0; k < 128; ++k) {
        float xk = h1[k];
#pragma unroll
        for (int j = 0; j < 64; ++j) h2[j] += xk * w2[k * 64 + j];
    }
#pragma unroll
    for (int j = 0; j < 64; ++j) {
        float v = h2[j] + B2[j];
        h2[j] = 0.5f * v * (1.0f + erff(v * 0.70710678118654752f));
    }
    float o[5];
#pragma unroll
    for (int j = 0; j < 5; ++j) o[j] = B3[j];
#pragma unroll
    for (int k = 0; k < 64; ++k) {
        float xk = h2[k];
#pragma unroll
        for (int j = 0; j < 5; ++j) o[j] += xk * W3[k * 5 + j];
    }
    float* yr = Y + (size_t)r * 5;
#pragma unroll
    for (int j = 0; j < 5; ++j) yr[j] = o[j];
}

extern "C" void kernel_launch(void* const* d_in, const int* in_sizes, int n_in,
                              void* d_out, int out_size, void* d_ws, size_t ws_size,
                              hipStream_t stream)
{
    const float* x   = (const float*)d_in[0];
    const int*   ei  = (const int*)d_in[1];
    const int*   srcs = ei;
    const int*   dsts = ei + N_EDGES;
    const float* ew  = (const float*)d_in[2];
    const float* cw0 = (const float*)d_in[3];  const float* cb0 = (const float*)d_in[4];
    const float* cw1 = (const float*)d_in[5];  const float* cb1 = (const float*)d_in[6];
    const float* cw2 = (const float*)d_in[7];  const float* cb2 = (const float*)d_in[8];
    const float* g0  = (const float*)d_in[9];  const float* be0 = (const float*)d_in[10];
    const float* g1  = (const float*)d_in[11]; const float* be1 = (const float*)d_in[12];
    const float* g2  = (const float*)d_in[13]; const float* be2 = (const float*)d_in[14];
    const float* mw1 = (const float*)d_in[15]; const float* mb1 = (const float*)d_in[16];
    const float* mw2 = (const float*)d_in[17]; const float* mb2 = (const float*)d_in[18];
    const float* mw3 = (const float*)d_in[19]; const float* mb3 = (const float*)d_in[20];
    float* out = (float*)d_out;

    char* ws = (char*)d_ws;
    size_t off = 0;
    auto alloc = [&](size_t b) { size_t o = off; off = (off + b + 511) & ~(size_t)511; return o; };

    int*   counts  = (int*)(ws + alloc((size_t)N_NODES * 4));
    int*   offsets = (int*)(ws + alloc((size_t)(N_NODES + 1) * 4));
    int*   cursor  = (int*)(ws + alloc((size_t)N_NODES * 4));
    int*   bsums   = (int*)(ws + alloc((size_t)NBLK_N * 4));
    float* stats   = (float*)(ws + alloc(3 * 128 * 4));   // stats[layer*128 ...]
    float* scsh    = (float*)(ws + alloc(3 * 128 * 4));
    long long* csr = (long long*)(ws + alloc((size_t)N_EDGES * 8));
    float* t       = (float*)(ws + alloc((size_t)N_NODES * HID * 4));
    float* h       = (float*)(ws + alloc((size_t)N_NODES * HID * 4));

    // ---- Build dst-CSR (packed 8B entries) ----
    init_zero<<<(N_NODES + 384 + BLK - 1) / BLK, BLK, 0, stream>>>(counts, stats);
    count_deg<<<NBLK_E, BLK, 0, stream>>>(dsts, counts, N_EDGES);
    scan1<<<NBLK_N, BLK, 0, stream>>>(counts, offsets, bsums, N_NODES);
    scan2<<<1, 512, 0, stream>>>(bsums, NBLK_N);
    scan3<<<NBLK_N, BLK, 0, stream>>>(counts, offsets, cursor, bsums, N_NODES);
    fill_csr<<<NBLK_E, BLK, 0, stream>>>(srcs, dsts, ew, cursor, csr, N_EDGES);

    const int2* csr2 = (const int2*)csr;

    // ---- Layer 0 ----
    mm_kernel<INC, HID, false><<<NBLK_N, BLK, 0, stream>>>(x, cw0, nullptr, nullptr, t, N_NODES);
    aggregate_bn<<<AGG_GRID, BLK, 0, stream>>>(t, offsets, csr2, cb0, h, stats, N_NODES);
    bn_finalize<<<1, 64, 0, stream>>>(stats, g0, be0, scsh, (float)N_NODES);

    // ---- Layer 1 ----
    mm_kernel<HID, HID, true><<<NBLK_N, BLK, 0, stream>>>(h, cw1, scsh, scsh + 64, t, N_NODES);
    aggregate_bn<<<AGG_GRID, BLK, 0, stream>>>(t, offsets, csr2, cb1, h, stats + 128, N_NODES);
    bn_finalize<<<1, 64, 0, stream>>>(stats + 128, g1, be1, scsh + 128, (float)N_NODES);

    // ---- Layer 2 ----
    mm_kernel<HID, HID, true><<<NBLK_N, BLK, 0, stream>>>(h, cw2, scsh + 128, scsh + 192, t, N_NODES);
    aggregate_bn<<<AGG_GRID, BLK, 0, stream>>>(t, offsets, csr2, cb2, h, stats + 256, N_NODES);
    bn_finalize<<<1, 64, 0, stream>>>(stats + 256, g2, be2, scsh + 256, (float)N_NODES);

    // ---- Fused MLP (BN of layer 2 folded in) ----
    mlp_fused<<<NBLK_N, BLK, 65536, stream>>>(h, mw1, mb1, mw2, mb2, mw3, mb3,
                                              scsh + 256, out, N_NODES);
}

// Round 3
// 1285.324 us; speedup vs baseline: 6.9273x; 6.9273x over previous
//
#include <hip/hip_runtime.h>
#include <math.h>

#define N_NODES 100000
#define N_EDGES 3200000
#define INC 128
#define HID 64

constexpr int BLK = 256;
constexpr int NBLK_N = (N_NODES + BLK - 1) / BLK;   // 391
constexpr int NBLK_E = (N_EDGES + BLK - 1) / BLK;   // 12500

// zero counts[N_NODES] and stats[3*128]
__global__ void init_zero(int* __restrict__ counts, float* __restrict__ stats) {
    int i = blockIdx.x * blockDim.x + threadIdx.x;
    if (i < N_NODES) counts[i] = 0;
    else if (i < N_NODES + 384) stats[i - N_NODES] = 0.f;
}

__global__ void count_deg(const int* __restrict__ dst, int* __restrict__ counts, int e) {
    int i = blockIdx.x * blockDim.x + threadIdx.x;
    if (i < e) atomicAdd(&counts[dst[i]], 1);
}

// block-level exclusive scan (within block), block totals to bsums
__global__ void scan1(const int* __restrict__ counts, int* __restrict__ offsets,
                      int* __restrict__ bsums, int n) {
    __shared__ int s[BLK];
    int i = blockIdx.x * BLK + threadIdx.x;
    int v = (i < n) ? counts[i] : 0;
    s[threadIdx.x] = v;
    __syncthreads();
    for (int d = 1; d < BLK; d <<= 1) {
        int t = (threadIdx.x >= d) ? s[threadIdx.x - d] : 0;
        __syncthreads();
        s[threadIdx.x] += t;
        __syncthreads();
    }
    if (i < n) offsets[i] = s[threadIdx.x] - v;  // exclusive
    if (threadIdx.x == BLK - 1) bsums[blockIdx.x] = s[BLK - 1];
}

// single-block exclusive scan of block sums (nb <= 512)
__global__ void scan2(int* __restrict__ bsums, int nb) {
    __shared__ int s[512];
    int v = (threadIdx.x < nb) ? bsums[threadIdx.x] : 0;
    s[threadIdx.x] = v;
    __syncthreads();
    for (int d = 1; d < 512; d <<= 1) {
        int t = (threadIdx.x >= d) ? s[threadIdx.x - d] : 0;
        __syncthreads();
        s[threadIdx.x] += t;
        __syncthreads();
    }
    if (threadIdx.x < nb) bsums[threadIdx.x] = s[threadIdx.x] - v;
}

__global__ void scan3(const int* __restrict__ counts, int* __restrict__ offsets,
                      int* __restrict__ cursor, const int* __restrict__ bsums, int n) {
    int i = blockIdx.x * BLK + threadIdx.x;
    if (i < n) {
        int o = offsets[i] + bsums[blockIdx.x];
        offsets[i] = o;
        cursor[i] = o;
        if (i == n - 1) offsets[n] = o + counts[i];
    }
}

// one packed 8B store per edge
__global__ void fill_csr(const int* __restrict__ src, const int* __restrict__ dst,
                         const float* __restrict__ ew, int* __restrict__ cursor,
                         long long* __restrict__ csr, int e) {
    int i = blockIdx.x * blockDim.x + threadIdx.x;
    if (i < e) {
        int d = dst[i];
        int pos = atomicAdd(&cursor[d], 1);
        unsigned long long v = (unsigned int)src[i] |
                               ((unsigned long long)__float_as_uint(ew[i]) << 32);
        __builtin_nontemporal_store((long long)v, csr + pos);
    }
}

// One wave per destination node (grid-stride); lane = channel.
// out = relu(sum ew * t[src] + bias); also accumulates BN sum/sumsq per block.
constexpr int AGG_GRID = 2048;
__global__ __launch_bounds__(BLK) void aggregate_bn(
    const float* __restrict__ t, const int* __restrict__ offs,
    const int2* __restrict__ csr, const float* __restrict__ bias,
    float* __restrict__ out, float* __restrict__ stats, int n)
{
    int lane = threadIdx.x & 63;
    int wid = threadIdx.x >> 6;  // 0..3
    int gwave = blockIdx.x * 4 + wid;
    int nwaves = gridDim.x * 4;
    float bval = bias[lane];
    float bsum = 0.f, bsum2 = 0.f;
    for (int node = gwave; node < n; node += nwaves) {
        int s0 = offs[node], s1 = offs[node + 1];
        float acc = 0.f;
        for (int base = s0; base < s1; base += 64) {
            int idx = base + lane;
            int e = (idx < s1) ? idx : (s1 - 1);
            int2 pk = csr[e];
            int srcv = pk.x;
            float eww = __int_as_float(pk.y);
            int cnt = min(64, s1 - base);
            for (int i = 0; i < cnt; ++i) {
                int s = __shfl(srcv, i, 64);
                float w = __shfl(eww, i, 64);
                acc += w * t[(size_t)s * HID + lane];
            }
        }
        float v = fmaxf(acc + bval, 0.f);
        out[(size_t)node * HID + lane] = v;
        bsum += v;
        bsum2 += v * v;
    }
    __shared__ float ls[4][64], ls2[4][64];
    ls[wid][lane] = bsum;
    ls2[wid][lane] = bsum2;
    __syncthreads();
    if (threadIdx.x < 64) {
        int c = threadIdx.x;
        float a = ls[0][c] + ls[1][c] + ls[2][c] + ls[3][c];
        float b = ls2[0][c] + ls2[1][c] + ls2[2][c] + ls2[3][c];
        atomicAdd(&stats[c], a);
        atomicAdd(&stats[64 + c], b);
    }
}

__global__ void bn_finalize(const float* __restrict__ stats, const float* __restrict__ g,
                            const float* __restrict__ be, float* __restrict__ scsh, float n) {
    int c = threadIdx.x;
    if (c < 64) {
        float mean = stats[c] / n;
        float var = stats[64 + c] / n - mean * mean;
        float s = 1.0f / sqrtf(var + 1e-5f);
        float sc = g[c] * s;
        scsh[c] = sc;
        scsh[64 + c] = be[c] - mean * sc;
    }
}

// Y[r,:] = (trans? X*sc+sh : X)[r,:] @ W   (one thread per row; W in LDS, broadcast reads)
template <int IN, int OUT, bool TRANS>
__global__ __launch_bounds__(BLK) void mm_kernel(
    const float* __restrict__ X, const float* __restrict__ W,
    const float* __restrict__ scale, const float* __restrict__ shift,
    float* __restrict__ Y, int n)
{
    __shared__ float Wl[IN * OUT];
    for (int i = threadIdx.x; i < IN * OUT; i += BLK) Wl[i] = W[i];
    __shared__ float sc[IN], sh[IN];
    if (TRANS) {
        for (int i = threadIdx.x; i < IN; i += BLK) {
            sc[i] = scale[i];
            sh[i] = shift[i];
        }
    }
    __syncthreads();
    int r = blockIdx.x * BLK + threadIdx.x;
    if (r >= n) return;
    float acc[OUT];
#pragma unroll
    for (int j = 0; j < OUT; ++j) acc[j] = 0.f;
    const float4* x4 = reinterpret_cast<const float4*>(X + (size_t)r * IN);
#pragma unroll 2
    for (int k4 = 0; k4 < IN / 4; ++k4) {
        float4 xv = x4[k4];
        float xs[4] = {xv.x, xv.y, xv.z, xv.w};
#pragma unroll
        for (int u = 0; u < 4; ++u) {
            int k = k4 * 4 + u;
            float xk = xs[u];
            if (TRANS) xk = xk * sc[k] + sh[k];
#pragma unroll
            for (int j = 0; j < OUT; ++j) acc[j] += xk * Wl[k * OUT + j];
        }
    }
    float* yr = Y + (size_t)r * OUT;
#pragma unroll
    for (int j = 0; j < OUT; ++j) yr[j] = acc[j];
}

__device__ __forceinline__ float gelu_f(float v) {
    return 0.5f * v * (1.0f + erff(v * 0.70710678118654752f));
}

// hb[r, half*64 + jj] = gelu((x*sc+sh) @ W1 + b1), column half per blockIdx.y
__global__ __launch_bounds__(BLK) void mlp1(
    const float* __restrict__ X, const float* __restrict__ W1,
    const float* __restrict__ B1, const float* __restrict__ scsh,
    float* __restrict__ HB, int n)
{
    __shared__ float Wl[64 * 64];
    __shared__ float sc[64], sh[64], bl[64];
    int half = blockIdx.y;
    for (int i = threadIdx.x; i < 64 * 64; i += BLK) {
        int k = i >> 6, jj = i & 63;
        Wl[i] = W1[k * 128 + half * 64 + jj];
    }
    if (threadIdx.x < 64) {
        sc[threadIdx.x] = scsh[threadIdx.x];
        sh[threadIdx.x] = scsh[64 + threadIdx.x];
        bl[threadIdx.x] = B1[half * 64 + threadIdx.x];
    }
    __syncthreads();
    int r = blockIdx.x * BLK + threadIdx.x;
    if (r >= n) return;
    float acc[64];
#pragma unroll
    for (int j = 0; j < 64; ++j) acc[j] = 0.f;
    const float4* x4 = reinterpret_cast<const float4*>(X + (size_t)r * 64);
#pragma unroll 2
    for (int k4 = 0; k4 < 16; ++k4) {
        float4 xv = x4[k4];
        float xs[4] = {xv.x, xv.y, xv.z, xv.w};
#pragma unroll
        for (int u = 0; u < 4; ++u) {
            int k = k4 * 4 + u;
            float xk = xs[u] * sc[k] + sh[k];
#pragma unroll
            for (int j = 0; j < 64; ++j) acc[j] += xk * Wl[k * 64 + j];
        }
    }
    float* yr = HB + (size_t)r * 128 + half * 64;
#pragma unroll
    for (int j = 0; j < 64; ++j) yr[j] = gelu_f(acc[j] + bl[j]);
}

// out[r,:] = gelu(hb @ W2 + b2) @ W3 + b3
__global__ __launch_bounds__(BLK) void mlp2(
    const float* __restrict__ HB, const float* __restrict__ W2,
    const float* __restrict__ B2, const float* __restrict__ W3,
    const float* __restrict__ B3, float* __restrict__ Y, int n)
{
    __shared__ float Wl[128 * 64];
    __shared__ float W3l[64 * 5];
    __shared__ float b2l[64], b3l[8];
    for (int i = threadIdx.x; i < 128 * 64; i += BLK) Wl[i] = W2[i];
    for (int i = threadIdx.x; i < 64 * 5; i += BLK) W3l[i] = W3[i];
    if (threadIdx.x < 64) b2l[threadIdx.x] = B2[threadIdx.x];
    if (threadIdx.x < 5) b3l[threadIdx.x] = B3[threadIdx.x];
    __syncthreads();
    int r = blockIdx.x * BLK + threadIdx.x;
    if (r >= n) return;
    float acc[64];
#pragma unroll
    for (int j = 0; j < 64; ++j) acc[j] = 0.f;
    const float4* x4 = reinterpret_cast<const float4*>(HB + (size_t)r * 128);
#pragma unroll 2
    for (int k4 = 0; k4 < 32; ++k4) {
        float4 xv = x4[k4];
        float xs[4] = {xv.x, xv.y, xv.z, xv.w};
#pragma unroll
        for (int u = 0; u < 4; ++u) {
            int k = k4 * 4 + u;
            float xk = xs[u];
#pragma unroll
            for (int j = 0; j < 64; ++j) acc[j] += xk * Wl[k * 64 + j];
        }
    }
    float o[5];
#pragma unroll
    for (int j = 0; j < 5; ++j) o[j] = b3l[j];
#pragma unroll
    for (int k = 0; k < 64; ++k) {
        float g = gelu_f(acc[k] + b2l[k]);
#pragma unroll
        for (int j = 0; j < 5; ++j) o[j] += g * W3l[k * 5 + j];
    }
    float* yr = Y + (size_t)r * 5;
#pragma unroll
    for (int j = 0; j < 5; ++j) yr[j] = o[j];
}

extern "C" void kernel_launch(void* const* d_in, const int* in_sizes, int n_in,
                              void* d_out, int out_size, void* d_ws, size_t ws_size,
                              hipStream_t stream)
{
    const float* x   = (const float*)d_in[0];
    const int*   ei  = (const int*)d_in[1];
    const int*   srcs = ei;
    const int*   dsts = ei + N_EDGES;
    const float* ew  = (const float*)d_in[2];
    const float* cw0 = (const float*)d_in[3];  const float* cb0 = (const float*)d_in[4];
    const float* cw1 = (const float*)d_in[5];  const float* cb1 = (const float*)d_in[6];
    const float* cw2 = (const float*)d_in[7];  const float* cb2 = (const float*)d_in[8];
    const float* g0  = (const float*)d_in[9];  const float* be0 = (const float*)d_in[10];
    const float* g1  = (const float*)d_in[11]; const float* be1 = (const float*)d_in[12];
    const float* g2  = (const float*)d_in[13]; const float* be2 = (const float*)d_in[14];
    const float* mw1 = (const float*)d_in[15]; const float* mb1 = (const float*)d_in[16];
    const float* mw2 = (const float*)d_in[17]; const float* mb2 = (const float*)d_in[18];
    const float* mw3 = (const float*)d_in[19]; const float* mb3 = (const float*)d_in[20];
    float* out = (float*)d_out;

    char* ws = (char*)d_ws;
    size_t off = 0;
    auto alloc = [&](size_t b) { size_t o = off; off = (off + b + 511) & ~(size_t)511; return o; };

    int*   counts  = (int*)(ws + alloc((size_t)N_NODES * 4));
    int*   offsets = (int*)(ws + alloc((size_t)(N_NODES + 1) * 4));
    int*   cursor  = (int*)(ws + alloc((size_t)N_NODES * 4));
    int*   bsums   = (int*)(ws + alloc((size_t)NBLK_N * 4));
    float* stats   = (float*)(ws + alloc(3 * 128 * 4));
    float* scsh    = (float*)(ws + alloc(3 * 128 * 4));
    size_t o_csr   = alloc((size_t)N_EDGES * 8);           // 25,600,000 B (512-mult)
    long long* csr = (long long*)(ws + o_csr);
    float* t       = (float*)(ws + alloc((size_t)N_NODES * HID * 4));  // contiguous after csr
    float* h       = (float*)(ws + alloc((size_t)N_NODES * HID * 4));
    // hb (N x 128 = 51.2 MB) aliases csr + t (dead after the last aggregate)
    float* hb      = (float*)(ws + o_csr);

    // ---- Build dst-CSR (packed 8B entries) ----
    init_zero<<<(N_NODES + 384 + BLK - 1) / BLK, BLK, 0, stream>>>(counts, stats);
    count_deg<<<NBLK_E, BLK, 0, stream>>>(dsts, counts, N_EDGES);
    scan1<<<NBLK_N, BLK, 0, stream>>>(counts, offsets, bsums, N_NODES);
    scan2<<<1, 512, 0, stream>>>(bsums, NBLK_N);
    scan3<<<NBLK_N, BLK, 0, stream>>>(counts, offsets, cursor, bsums, N_NODES);
    fill_csr<<<NBLK_E, BLK, 0, stream>>>(srcs, dsts, ew, cursor, csr, N_EDGES);

    const int2* csr2 = (const int2*)csr;

    // ---- Layer 0 ----
    mm_kernel<INC, HID, false><<<NBLK_N, BLK, 0, stream>>>(x, cw0, nullptr, nullptr, t, N_NODES);
    aggregate_bn<<<AGG_GRID, BLK, 0, stream>>>(t, offsets, csr2, cb0, h, stats, N_NODES);
    bn_finalize<<<1, 64, 0, stream>>>(stats, g0, be0, scsh, (float)N_NODES);

    // ---- Layer 1 ----
    mm_kernel<HID, HID, true><<<NBLK_N, BLK, 0, stream>>>(h, cw1, scsh, scsh + 64, t, N_NODES);
    aggregate_bn<<<AGG_GRID, BLK, 0, stream>>>(t, offsets, csr2, cb1, h, stats + 128, N_NODES);
    bn_finalize<<<1, 64, 0, stream>>>(stats + 128, g1, be1, scsh + 128, (float)N_NODES);

    // ---- Layer 2 ----
    mm_kernel<HID, HID, true><<<NBLK_N, BLK, 0, stream>>>(h, cw2, scsh + 128, scsh + 192, t, N_NODES);
    aggregate_bn<<<AGG_GRID, BLK, 0, stream>>>(t, offsets, csr2, cb2, h, stats + 256, N_NODES);
    bn_finalize<<<1, 64, 0, stream>>>(stats + 256, g2, be2, scsh + 256, (float)N_NODES);

    // ---- MLP: two lean kernels (no spills) ----
    mlp1<<<dim3(NBLK_N, 2), BLK, 0, stream>>>(h, mw1, mb1, scsh + 256, hb, N_NODES);
    mlp2<<<NBLK_N, BLK, 0, stream>>>(hb, mw2, mb2, mw3, mb3, out, N_NODES);
}